// Round 1
// baseline (888.748 us; speedup 1.0000x reference)
//
#include <hip/hip_runtime.h>

#define N_SRC   100000
#define N_NEIGH 20
#define DRAW    256
#define DH      128
#define DMSG    128
#define DNEI    128
#define LDS_PAD 8   // +8 bf16 = 16B: keeps 16B alignment, breaks 16-way bank conflict

typedef __bf16 bf16x8 __attribute__((ext_vector_type(8)));
typedef float  floatx4 __attribute__((ext_vector_type(4)));

// ---- kernel 1: cast weights to bf16, transposed to [n][k] so each MFMA
// B-fragment (n = lane&15 fixed, k = quad*8..+8 contiguous) is one 16B load.
__global__ void convert_weights(const float* __restrict__ W1,
                                const float* __restrict__ W2,
                                const float* __restrict__ Wn,
                                __bf16* __restrict__ W1t,
                                __bf16* __restrict__ W2t,
                                __bf16* __restrict__ Wnt) {
    int i = blockIdx.x * 256 + threadIdx.x;           // 0..65535
    if (i < 32768) {                                  // W1t[n][k], n<128, k<256
        int n = i >> 8, k = i & 255;
        W1t[i] = (__bf16)W1[k * 128 + n];
    } else if (i < 49152) {                           // W2t[n][k], 128x128
        int j = i - 32768;
        int n = j >> 7, k = j & 127;
        W2t[j] = (__bf16)W2[k * 128 + n];
    } else {                                          // Wnt[n][k], 128x128
        int j = i - 49152;
        int n = j >> 7, k = j & 127;
        Wnt[j] = (__bf16)Wn[k * 128 + n];
    }
}

// ---- kernel 2: fully fused. Block = 256 threads (4 waves) = 64 sources.
// Phase A: gather 20 neighbor rows/source, mean-pool -> agg LDS (bf16).
// Phase B: GEMM1 h=relu(raw@W1+b1) via mfma_16x16x32_bf16 -> hbuf LDS.
// Phase C: GEMM2 (h@W2) + GEMM3 (agg@Wn) fused, epilogue relu+relu+add -> out.
__global__ __launch_bounds__(256)
void fused_kernel(const float* __restrict__ raw,
                  const int*   __restrict__ neigh,
                  const float* __restrict__ memv,
                  const float* __restrict__ b1,
                  const float* __restrict__ b2,
                  const float* __restrict__ bn,
                  const __bf16* __restrict__ W1t,
                  const __bf16* __restrict__ W2t,
                  const __bf16* __restrict__ Wnt,
                  float* __restrict__ out) {
    __shared__ __bf16 agg [64][DNEI + LDS_PAD];
    __shared__ __bf16 hbuf[64][DH   + LDS_PAD];

    const int tid = threadIdx.x;
    const int s0  = blockIdx.x * 64;

    // -------- Phase A: gather + mean-pool --------
    {
        const int grp = tid >> 5;     // 8 groups of 32 lanes
        const int l32 = tid & 31;
        for (int sl = grp; sl < 64; sl += 8) {
            const int s = s0 + sl;
            float4 acc = make_float4(0.f, 0.f, 0.f, 0.f);
            if (s < N_SRC) {
                int myidx = 0;
                if (l32 < N_NEIGH) myidx = neigh[s * N_NEIGH + l32];
                #pragma unroll
                for (int n = 0; n < N_NEIGH; ++n) {
                    int idx = __shfl(myidx, n, 32);   // broadcast within 32-group
                    const float4* row =
                        reinterpret_cast<const float4*>(memv + (size_t)idx * DNEI);
                    float4 v = row[l32];              // 32 lanes x 16B = one 512B row
                    acc.x += v.x; acc.y += v.y; acc.z += v.z; acc.w += v.w;
                }
                const float inv = 1.0f / N_NEIGH;
                acc.x *= inv; acc.y *= inv; acc.z *= inv; acc.w *= inv;
            }
            __bf16* dst = &agg[sl][l32 * 4];
            dst[0] = (__bf16)acc.x; dst[1] = (__bf16)acc.y;
            dst[2] = (__bf16)acc.z; dst[3] = (__bf16)acc.w;
        }
    }

    const int lane = tid & 63;
    const int wave = tid >> 6;       // 0..3, each wave owns 16 source rows
    const int mr   = lane & 15;      // A: m-index / B: n-index / D: col
    const int quad = lane >> 4;      // 0..3

    // -------- Phase B: GEMM1 h = relu(raw @ W1 + b1) --------
    {
        int rowg = s0 + wave * 16 + mr;
        int rowc = rowg < N_SRC ? rowg : N_SRC - 1;   // clamp; results masked at store
        const float* ar = raw + (size_t)rowc * DRAW;

        floatx4 acc[8];
        #pragma unroll
        for (int nt = 0; nt < 8; ++nt) { floatx4 z = {0.f,0.f,0.f,0.f}; acc[nt] = z; }

        #pragma unroll
        for (int kk = 0; kk < DRAW; kk += 32) {
            const int kb = kk + quad * 8;
            float4 a0 = *reinterpret_cast<const float4*>(ar + kb);
            float4 a1 = *reinterpret_cast<const float4*>(ar + kb + 4);
            bf16x8 af;
            af[0]=(__bf16)a0.x; af[1]=(__bf16)a0.y; af[2]=(__bf16)a0.z; af[3]=(__bf16)a0.w;
            af[4]=(__bf16)a1.x; af[5]=(__bf16)a1.y; af[6]=(__bf16)a1.z; af[7]=(__bf16)a1.w;
            #pragma unroll
            for (int nt = 0; nt < 8; ++nt) {
                bf16x8 bf = *reinterpret_cast<const bf16x8*>(
                    W1t + (nt * 16 + mr) * DRAW + kb);
                acc[nt] = __builtin_amdgcn_mfma_f32_16x16x32_bf16(af, bf, acc[nt], 0, 0, 0);
            }
        }
        // epilogue: +b1, relu, -> hbuf (C/D layout: col=lane&15, row=quad*4+r)
        #pragma unroll
        for (int nt = 0; nt < 8; ++nt) {
            const int col  = nt * 16 + mr;
            const float bias = b1[col];
            #pragma unroll
            for (int r = 0; r < 4; ++r) {
                int mrow = wave * 16 + quad * 4 + r;
                float v = acc[nt][r] + bias;
                hbuf[mrow][col] = (__bf16)(v > 0.f ? v : 0.f);
            }
        }
    }

    __syncthreads();   // covers agg writes (Phase A) + hbuf writes (Phase B)

    // -------- Phase C: GEMM2 (h@W2) + GEMM3 (agg@Wn), fused epilogue --------
    {
        floatx4 acc2[8], acc3[8];
        #pragma unroll
        for (int nt = 0; nt < 8; ++nt) {
            floatx4 z = {0.f,0.f,0.f,0.f}; acc2[nt] = z; acc3[nt] = z;
        }

        #pragma unroll
        for (int kk = 0; kk < DH; kk += 32) {
            const int kb = kk + quad * 8;
            bf16x8 af2 = *reinterpret_cast<const bf16x8*>(&hbuf[wave * 16 + mr][kb]);
            bf16x8 af3 = *reinterpret_cast<const bf16x8*>(&agg [wave * 16 + mr][kb]);
            #pragma unroll
            for (int nt = 0; nt < 8; ++nt) {
                bf16x8 bw2 = *reinterpret_cast<const bf16x8*>(
                    W2t + (nt * 16 + mr) * DH + kb);
                acc2[nt] = __builtin_amdgcn_mfma_f32_16x16x32_bf16(af2, bw2, acc2[nt], 0, 0, 0);
                bf16x8 bw3 = *reinterpret_cast<const bf16x8*>(
                    Wnt + (nt * 16 + mr) * DNEI + kb);
                acc3[nt] = __builtin_amdgcn_mfma_f32_16x16x32_bf16(af3, bw3, acc3[nt], 0, 0, 0);
            }
        }

        #pragma unroll
        for (int nt = 0; nt < 8; ++nt) {
            const int col = nt * 16 + mr;
            const float bb2 = b2[col];
            const float bbn = bn[col];
            #pragma unroll
            for (int r = 0; r < 4; ++r) {
                int rowl = wave * 16 + quad * 4 + r;
                int rowg = s0 + rowl;
                if (rowg < N_SRC) {
                    float va = acc2[nt][r] + bb2; va = va > 0.f ? va : 0.f;
                    float vb = acc3[nt][r] + bbn; vb = vb > 0.f ? vb : 0.f;
                    out[(size_t)rowg * DMSG + col] = va + vb;
                }
            }
        }
    }
}

extern "C" void kernel_launch(void* const* d_in, const int* in_sizes, int n_in,
                              void* d_out, int out_size, void* d_ws, size_t ws_size,
                              hipStream_t stream) {
    const float* raw   = (const float*)d_in[0];
    const int*   neigh = (const int*)  d_in[1];
    const float* memv  = (const float*)d_in[2];
    const float* W1    = (const float*)d_in[3];
    const float* b1    = (const float*)d_in[4];
    const float* W2    = (const float*)d_in[5];
    const float* b2    = (const float*)d_in[6];
    const float* Wn    = (const float*)d_in[7];
    const float* bn    = (const float*)d_in[8];
    float* out = (float*)d_out;

    // ws layout: W1t bf16 [128][256] (64KB) | W2t [128][128] (32KB) | Wnt [128][128] (32KB)
    __bf16* W1t = (__bf16*)d_ws;
    __bf16* W2t = W1t + 32768;
    __bf16* Wnt = W2t + 16384;

    convert_weights<<<dim3(256), dim3(256), 0, stream>>>(W1, W2, Wn, W1t, W2t, Wnt);

    const int nblocks = (N_SRC + 63) / 64;
    fused_kernel<<<dim3(nblocks), dim3(256), 0, stream>>>(
        raw, neigh, memv, b1, b2, bn, W1t, W2t, Wnt, out);
}